// Round 3
// baseline (17681.519 us; speedup 1.0000x reference)
//
#include <hip/hip_runtime.h>
#include <stdint.h>

typedef unsigned int u32;
typedef unsigned short u16;

// ---- problem dims ----
#define TT     256
#define LATENT 512
#define NINTER 216
#define NCMD   143
#define NMOT   153
// packed (bf16-pair) K dimensions, all even-padded; pads carry ZERO weights so
// pad activations may be garbage.
#define KZ2   261   // LSTM xc: [xt(9), pad, h_rec(512)] = 522/2
#define K2_0  113   // L0 xc:  [xt(9), pad, h_lstm 0:216] = 226/2
#define K2_1  180   // L1 xc:  [i0(216), h_lstm 216:359, pad] = 360/2
#define K2_2  149   // L2 xc:  [i1(143), pad, h358(w=0), h_lstm 359:512] = 298/2
#define NT0   864   // 4*216 fused (w1,w2,wa,wb) interleaved tasks
#define NT1   572   // 4*143
#define NT2   612   // 4*153
// workspace layout (u32 words)
#define OFF_L0  (KZ2*2048)            // 534528
#define OFF_L1  (OFF_L0 + K2_0*NT0)   // 632160
#define OFF_L2  (OFF_L1 + K2_1*NT1)   // 735120
#define WS_WORDS (OFF_L2 + K2_2*NT2)  // 826308  (~3.15 MiB)

__device__ __forceinline__ u16 f2bf(float f){
  u32 u = __builtin_bit_cast(u32, f);
  u += 0x7FFFu + ((u >> 16) & 1u);     // RNE
  return (u16)(u >> 16);
}
__device__ __forceinline__ u32 packbf(float lo, float hi){
  return (u32)f2bf(lo) | ((u32)f2bf(hi) << 16);
}
// v_dot2_f32_bf16: d = a.lo*b.lo + a.hi*b.hi + c  (f32 accumulate)
__device__ __forceinline__ float bdot(u32 a, u32 b, float c){
  float d;
  asm("v_dot2_f32_bf16 %0, %1, %2, %3" : "=v"(d) : "v"(a), "v"(b), "v"(c));
  return d;
}
__device__ __forceinline__ float sigm(float x){ return 1.0f/(1.0f + __expf(-x)); }
__device__ __forceinline__ float tanh_(float x){ return 1.0f - 2.0f/(1.0f + __expf(2.0f*x)); }
// acc order per output: (w1, w2, wa, wb)
__device__ __forceinline__ float cfc_out(float4 a){
  float ti = sigm(a.w - a.z);
  return tanh_(a.x)*(1.0f - ti) + ti*tanh_(a.y);
}

// ---------------- weight prep: mask, bf16-pack, k-major transpose ----------------
__device__ __forceinline__ float l0val(const float* W, const int* M, int o, int k){
  if (k == 9 || k >= 226) return 0.f;
  int ki = (k < 9) ? k : k - 1;                 // D=225
  float w = W[o*225 + ki];
  if (M) w *= (float)M[o*225 + ki];
  return w;
}
__device__ __forceinline__ float l1val(const float* W, const int* M, int o, int k){
  if (k >= 359) return 0.f;                     // D=359
  float w = W[o*359 + k];
  if (M) w *= (float)M[o*359 + k];
  return w;
}
__device__ __forceinline__ float l2val(const float* W, const int* M, int o, int k){
  if (k == 143 || k == 144 || k >= 298) return 0.f;  // D=296; slot144 = h358 (zero weight)
  int ki = (k < 143) ? k : k - 2;
  float w = W[o*296 + ki];
  if (M) w *= (float)M[o*296 + ki];
  return w;
}

__global__ void prep_kernel(
    const float* __restrict__ wi, const float* __restrict__ wr,
    const float* __restrict__ w10,const float* __restrict__ w20,const float* __restrict__ wa0,const float* __restrict__ wb0,const int* __restrict__ m0,
    const float* __restrict__ w11,const float* __restrict__ w21,const float* __restrict__ wa1,const float* __restrict__ wb1,const int* __restrict__ m1,
    const float* __restrict__ w12,const float* __restrict__ w22,const float* __restrict__ wa2,const float* __restrict__ wb2,const int* __restrict__ m2,
    u32* __restrict__ ws)
{
  for (int i = blockIdx.x*blockDim.x + threadIdx.x; i < WS_WORDS; i += gridDim.x*blockDim.x){
    float lo, hi;
    if (i < OFF_L0){
      int k2 = i >> 11, row = i & 2047;
      int k0 = 2*k2, k1 = k0 + 1;
      lo = (k0 < 9) ? wi[row*9+k0] : (k0 == 9) ? 0.f : wr[row*512 + k0 - 10];
      hi = (k1 < 9) ? wi[row*9+k1] : (k1 == 9) ? 0.f : wr[row*512 + k1 - 10];
    } else if (i < OFF_L1){
      int loc = i - OFF_L0;
      int k2 = loc / NT0, rem = loc - k2*NT0;
      int o = rem >> 2, m = rem & 3;
      const float* W = (m==0)?w10:(m==1)?w20:(m==2)?wa0:wb0;
      const int* M = (m < 2) ? m0 : nullptr;
      lo = l0val(W, M, o, 2*k2); hi = l0val(W, M, o, 2*k2+1);
    } else if (i < OFF_L2){
      int loc = i - OFF_L1;
      int k2 = loc / NT1, rem = loc - k2*NT1;
      int o = rem >> 2, m = rem & 3;
      const float* W = (m==0)?w11:(m==1)?w21:(m==2)?wa1:wb1;
      const int* M = (m < 2) ? m1 : nullptr;
      lo = l1val(W, M, o, 2*k2); hi = l1val(W, M, o, 2*k2+1);
    } else {
      int loc = i - OFF_L2;
      int k2 = loc / NT2, rem = loc - k2*NT2;
      int o = rem >> 2, m = rem & 3;
      const float* W = (m==0)?w12:(m==1)?w22:(m==2)?wa2:wb2;
      const int* M = (m < 2) ? m2 : nullptr;
      lo = l2val(W, M, o, 2*k2); hi = l2val(W, M, o, 2*k2+1);
    }
    ws[i] = packbf(lo, hi);
  }
}

// ---------------- persistent recurrent kernel ----------------
// grid 64, block 1024. thread: b = tid&1 (batch within pair), v = tid>>1.
// Adjacent lanes (b=0/1) read identical weight words -> wave-level dedup.
__global__ __launch_bounds__(1024) void liquid_rnn(
    const float* __restrict__ x, const float* __restrict__ dtp,
    const float* __restrict__ lstm_bi,
    const float* __restrict__ b10, const float* __restrict__ b20,
    const float* __restrict__ ba0, const float* __restrict__ bb0,
    const float* __restrict__ b11, const float* __restrict__ b21,
    const float* __restrict__ ba1, const float* __restrict__ bb1,
    const float* __restrict__ b12, const float* __restrict__ b22,
    const float* __restrict__ ba2, const float* __restrict__ bb2,
    const u32* __restrict__ ws, float* __restrict__ out)
{
  __shared__ u32 xtp[2][8];                    // packed [xt(9),0]
  __shared__ u32 hrecp[2][256];                // packed recurrent h (CfC outs)
  __shared__ u32 hlp[2][256];                  // packed LSTM h
  __shared__ __align__(16) float zf[2][2048];  // raw LSTM gate pre-activations
  __shared__ __align__(16) float accL[2][NT0]; // CfC dot results (4 per out)
  __shared__ float bound[2];                   // i1[142] boundary stash

  const int tid = threadIdx.x;
  const int b   = tid & 1;
  const int v   = tid >> 1;
  const int bg  = blockIdx.x*2 + b;

  // hoisted biases (constant across t)
  const float lb0 = lstm_bi[4*v+0], lb1 = lstm_bi[4*v+1];
  const float lb2 = lstm_bi[4*v+2], lb3 = lstm_bi[4*v+3];
  const int t1_0 = (v + 512 < NT0) ? v + 512 : v;
  const int t1_1 = (v + 512 < NT1) ? v + 512 : v;
  const int t1_2 = (v + 512 < NT2) ? v + 512 : v;
  auto biasL0 = [&](int tau){ int m=tau&3, o=tau>>2; return m==0?b10[o]:m==1?b20[o]:m==2?ba0[o]:bb0[o]; };
  auto biasL1 = [&](int tau){ int m=tau&3, o=tau>>2; return m==0?b11[o]:m==1?b21[o]:m==2?ba1[o]:bb1[o]; };
  auto biasL2 = [&](int tau){ int m=tau&3, o=tau>>2; return m==0?b12[o]:m==1?b22[o]:m==2?ba2[o]:bb2[o]; };
  const float bc00 = biasL0(v), bc01 = biasL0(t1_0);
  const float bc10 = biasL1(v), bc11 = biasL1(t1_1);
  const float bc20 = biasL2(v), bc21 = biasL2(t1_2);

  // init: h_rec(0)=0, xt(0)
  if (v < 256) hrecp[b][v] = 0u;
  if (v < 5){
    int k0 = 2*v, k1 = 2*v+1;
    float e0 = (k0 < 8) ? x[(bg*TT)*8 + k0] : ((k0==8) ? dtp[bg*TT] : 0.f);
    float e1 = (k1 < 8) ? x[(bg*TT)*8 + k1] : ((k1==8) ? dtp[bg*TT] : 0.f);
    xtp[b][v] = packbf(e0, e1);
  }
  float creg = 0.f;
  __syncthreads();

  const u32* wz  = ws;
  const u32* wl0 = ws + OFF_L0;
  const u32* wl1 = ws + OFF_L1;
  const u32* wl2 = ws + OFF_L2;

  for (int t = 0; t < TT; ++t){
    // ---- phase 1: LSTM gate dots (rows 4v..4v+3 of z for batch b) ----
    {
      const u32* p = wz + 4*v;
      float a0=lb0, a1=lb1, a2=lb2, a3=lb3;
      #pragma unroll
      for (int k2 = 0; k2 < 5; ++k2){
        uint4 w = *(const uint4*)p; p += 2048;
        u32 xv = xtp[b][k2];
        a0=bdot(w.x,xv,a0); a1=bdot(w.y,xv,a1); a2=bdot(w.z,xv,a2); a3=bdot(w.w,xv,a3);
      }
      #pragma unroll 8
      for (int k2 = 0; k2 < 256; ++k2){
        uint4 w = *(const uint4*)p; p += 2048;
        u32 xv = hrecp[b][k2];
        a0=bdot(w.x,xv,a0); a1=bdot(w.y,xv,a1); a2=bdot(w.z,xv,a2); a3=bdot(w.w,xv,a3);
      }
      *(float4*)&zf[b][4*v] = make_float4(a0,a1,a2,a3);
    }
    __syncthreads();
    // ---- phase 2: LSTM pointwise (neuron v, batch b), pack h_lstm ----
    {
      float zi  = zf[b][v],        zig = zf[b][v+512];
      float zfg = zf[b][v+1024],   zog = zf[b][v+1536];
      creg = creg * sigm(zfg + 1.0f) + tanh_(zi) * sigm(zig);
      float hl_new = tanh_(creg) * sigm(zog);
      if (t == TT-1) out[65536 + bg*LATENT + v] = creg;
      float part = __shfl_down(hl_new, 2);     // (b,v+1) lives at tid+2
      if ((v & 1) == 0) hlp[b][v >> 1] = packbf(hl_new, part);
    }
    __syncthreads();
    // ---- phase 3: CfC layer0 dots ----
    {
      const u32* p0 = wl0 + v; const u32* p1 = wl0 + t1_0;
      float a0 = bc00, a1 = bc01;
      #pragma unroll
      for (int k2 = 0; k2 < 5; ++k2){
        u32 xv = xtp[b][k2];
        a0 = bdot(p0[0], xv, a0); a1 = bdot(p1[0], xv, a1);
        p0 += NT0; p1 += NT0;
      }
      #pragma unroll 4
      for (int k2 = 0; k2 < 108; ++k2){
        u32 xv = hlp[b][k2];
        a0 = bdot(p0[0], xv, a0); a1 = bdot(p1[0], xv, a1);
        p0 += NT0; p1 += NT0;
      }
      accL[b][v] = a0;
      if (v + 512 < NT0) accL[b][v+512] = a1;
    }
    __syncthreads();
    // ---- phase 4: layer0 combine -> i0 = h_rec[0:216] ----
    if (v < 108){
      float4 A0 = *(const float4*)&accL[b][8*v];
      float4 A1 = *(const float4*)&accL[b][8*v+4];
      float o0 = cfc_out(A0), o1 = cfc_out(A1);
      hrecp[b][v] = packbf(o0, o1);
      if (t == TT-1){ out[bg*LATENT + 2*v] = o0; out[bg*LATENT + 2*v+1] = o1; }
    }
    __syncthreads();
    // ---- phase 5: CfC layer1 dots ----
    {
      const u32* p0 = wl1 + v; const u32* p1 = wl1 + t1_1;
      float a0 = bc10, a1 = bc11;
      #pragma unroll 4
      for (int k2 = 0; k2 < 108; ++k2){
        u32 xv = hrecp[b][k2];
        a0 = bdot(p0[0], xv, a0); a1 = bdot(p1[0], xv, a1);
        p0 += NT1; p1 += NT1;
      }
      #pragma unroll 4
      for (int k2 = 108; k2 < 180; ++k2){
        u32 xv = hlp[b][k2];
        a0 = bdot(p0[0], xv, a0); a1 = bdot(p1[0], xv, a1);
        p0 += NT1; p1 += NT1;
      }
      accL[b][v] = a0;
      if (v + 512 < NT1) accL[b][v+512] = a1;
    }
    __syncthreads();
    // ---- phase 6: layer1 combine -> i1 = h_rec[216:359] ----
    if (v < 72){
      float4 A0 = *(const float4*)&accL[b][8*v];
      float o0 = cfc_out(A0);
      float o1 = 0.f;
      if (v < 71){
        float4 A1 = *(const float4*)&accL[b][8*v+4];
        o1 = cfc_out(A1);
      } else {
        bound[b] = o0;                          // i1[142] = h_rec[358]
      }
      hrecp[b][108+v] = packbf(o0, o1);         // word 179 odd half fixed in phase 8
      if (t == TT-1){
        out[bg*LATENT + NINTER + 2*v] = o0;
        if (v < 71) out[bg*LATENT + NINTER + 2*v + 1] = o1;
      }
    }
    __syncthreads();
    // ---- phase 7: CfC layer2 dots ----
    {
      const u32* p0 = wl2 + v; const u32* p1 = wl2 + t1_2;
      float a0 = bc20, a1 = bc21;
      #pragma unroll 4
      for (int k2 = 0; k2 < 72; ++k2){
        u32 xv = hrecp[b][108+k2];
        a0 = bdot(p0[0], xv, a0); a1 = bdot(p1[0], xv, a1);
        p0 += NT2; p1 += NT2;
      }
      #pragma unroll 4
      for (int k2 = 72; k2 < 149; ++k2){
        u32 xv = hlp[b][107+k2];
        a0 = bdot(p0[0], xv, a0); a1 = bdot(p1[0], xv, a1);
        p0 += NT2; p1 += NT2;
      }
      accL[b][v] = a0;
      if (v + 512 < NT2) accL[b][v+512] = a1;
    }
    __syncthreads();
    // ---- phase 8: layer2 combine -> i2 = h_rec[359:512]; prefetch xt(t+1) ----
    if (v < 77){
      if (v == 0){
        float4 A = *(const float4*)&accL[b][0];
        float o = cfc_out(A);                   // i2[0] = h_rec[359]
        hrecp[b][179] = packbf(bound[b], o);
        if (t == TT-1) out[bg*LATENT + 359] = o;
      } else {
        int j0 = 2*v - 1, j1 = 2*v;             // i2 indices
        float4 A0 = *(const float4*)&accL[b][4*j0];
        float4 A1 = *(const float4*)&accL[b][4*j1];
        float o0 = cfc_out(A0), o1 = cfc_out(A1);
        hrecp[b][179+v] = packbf(o0, o1);
        if (t == TT-1){
          out[bg*LATENT + 359 + j0] = o0;
          out[bg*LATENT + 359 + j1] = o1;
        }
      }
    }
    if (v >= 128 && v < 133 && t + 1 < TT){
      int w = v - 128;
      int k0 = 2*w, k1 = 2*w+1;
      float e0 = (k0 < 8) ? x[(bg*TT + t+1)*8 + k0] : ((k0==8) ? dtp[bg*TT + t+1] : 0.f);
      float e1 = (k1 < 8) ? x[(bg*TT + t+1)*8 + k1] : ((k1==8) ? dtp[bg*TT + t+1] : 0.f);
      xtp[b][w] = packbf(e0, e1);
    }
    __syncthreads();
  }
}

extern "C" void kernel_launch(void* const* d_in, const int* in_sizes, int n_in,
                              void* d_out, int out_size, void* d_ws, size_t ws_size,
                              hipStream_t stream)
{
  (void)in_sizes; (void)n_in; (void)out_size; (void)ws_size;
  const float* x   = (const float*)d_in[0];
  const float* dt  = (const float*)d_in[1];
  const float* wi  = (const float*)d_in[2];
  const float* wr  = (const float*)d_in[3];
  const float* bi  = (const float*)d_in[4];
  const float* w10 = (const float*)d_in[5];  const float* b10 = (const float*)d_in[6];
  const float* w20 = (const float*)d_in[7];  const float* b20 = (const float*)d_in[8];
  const float* wa0 = (const float*)d_in[9];  const float* ba0 = (const float*)d_in[10];
  const float* wb0 = (const float*)d_in[11]; const float* bb0 = (const float*)d_in[12];
  const float* w11 = (const float*)d_in[13]; const float* b11 = (const float*)d_in[14];
  const float* w21 = (const float*)d_in[15]; const float* b21 = (const float*)d_in[16];
  const float* wa1 = (const float*)d_in[17]; const float* ba1 = (const float*)d_in[18];
  const float* wb1 = (const float*)d_in[19]; const float* bb1 = (const float*)d_in[20];
  const float* w12 = (const float*)d_in[21]; const float* b12 = (const float*)d_in[22];
  const float* w22 = (const float*)d_in[23]; const float* b22 = (const float*)d_in[24];
  const float* wa2 = (const float*)d_in[25]; const float* ba2 = (const float*)d_in[26];
  const float* wb2 = (const float*)d_in[27]; const float* bb2 = (const float*)d_in[28];
  const int* m0 = (const int*)d_in[29];
  const int* m1 = (const int*)d_in[30];
  const int* m2 = (const int*)d_in[31];

  u32* ws   = (u32*)d_ws;          // needs WS_WORDS*4 ≈ 3.16 MiB
  float* out = (float*)d_out;      // f32: h[128*512] then c[128*512]

  prep_kernel<<<dim3(808), dim3(1024), 0, stream>>>(
      wi, wr,
      w10,w20,wa0,wb0,m0,
      w11,w21,wa1,wb1,m1,
      w12,w22,wa2,wb2,m2,
      ws);

  liquid_rnn<<<dim3(64), dim3(1024), 0, stream>>>(
      x, dt, bi,
      b10,b20,ba0,bb0,
      b11,b21,ba1,bb1,
      b12,b22,ba2,bb2,
      ws, out);
}

// Round 4
// 17339.259 us; speedup vs baseline: 1.0197x; 1.0197x over previous
//
#include <hip/hip_runtime.h>
#include <stdint.h>

typedef unsigned int u32;
typedef unsigned short u16;

// ---- problem dims ----
#define TT     256
#define LATENT 512
// padded k2 (bf16-pair) dims and task dims
#define KZ2P 264    // LSTM xc slots: [xt(9), pad, h0..h358, pad, h359..h511] = 524 -> 262 words, pad to 264
#define K0P  120    // L0 real 113 words
#define K1P  192    // L1 real 180 words
#define K2P  156    // L2 real 149 words
#define NT0  864
#define NT1  572
#define NT2  612
#define NT0P 896
#define NT1P 640
#define NT2P 640
// workspace layout (u32 words)
#define OFF1 (KZ2P*2048)            // 540672
#define OFF2 (OFF1 + K0P*NT0P)      // 648192
#define OFF3 (OFF2 + K1P*NT1P)      // 771072
#define WS_WORDS (OFF3 + K2P*NT2P)  // 870912 (~3.32 MiB)

__device__ __forceinline__ u16 f2bf(float f){
  u32 u = __builtin_bit_cast(u32, f);
  u += 0x7FFFu + ((u >> 16) & 1u);     // RNE
  return (u16)(u >> 16);
}
__device__ __forceinline__ u32 packbf(float lo, float hi){
  return (u32)f2bf(lo) | ((u32)f2bf(hi) << 16);
}
__device__ __forceinline__ float bdot(u32 a, u32 b, float c){
  float d;
  asm("v_dot2_f32_bf16 %0, %1, %2, %3" : "=v"(d) : "v"(a), "v"(b), "v"(c));
  return d;
}
__device__ __forceinline__ float sigm(float x){ return 1.0f/(1.0f + __expf(-x)); }
__device__ __forceinline__ float tanh_(float x){ return 1.0f - 2.0f/(1.0f + __expf(2.0f*x)); }

template<int N>
__device__ __forceinline__ void waitvm(){
  asm volatile("s_waitcnt vmcnt(%0)" :: "i"(N) : "memory");
}
__device__ __forceinline__ void block_sync(){
  asm volatile("s_waitcnt lgkmcnt(0)" ::: "memory");
  __builtin_amdgcn_s_barrier();
  asm volatile("" ::: "memory");
}
__device__ __forceinline__ void gl16(const void* g, u32* l){
  __builtin_amdgcn_global_load_lds((const __attribute__((address_space(1))) u32*)g,
                                   (__attribute__((address_space(3))) u32*)l, 16, 0, 0);
}

// ---------------- weight prep: mask, bf16-pack, k-major, padded ----------------
__device__ __forceinline__ float lstmval(const float* wi, const float* wr, int r, int s){
  if (s < 9)  return wi[r*9 + s];
  if (s == 9 || s == 369 || s >= 523) return 0.f;
  if (s < 369) return wr[r*512 + s - 10];   // h0..h358
  return wr[r*512 + s - 11];                // h359..h511 (extra pad at slot 369)
}
__device__ __forceinline__ float l0val(const float* W, const int* M, int o, int k){
  if (k == 9 || k >= 226) return 0.f;
  int ki = (k < 9) ? k : k - 1;                 // D=225
  float w = W[o*225 + ki];
  if (M) w *= (float)M[o*225 + ki];
  return w;
}
__device__ __forceinline__ float l1val(const float* W, const int* M, int o, int k){
  if (k >= 359) return 0.f;                     // D=359
  float w = W[o*359 + k];
  if (M) w *= (float)M[o*359 + k];
  return w;
}
__device__ __forceinline__ float l2val(const float* W, const int* M, int o, int k){
  if (k == 143 || k == 144 || k >= 298) return 0.f;  // D=296; slot144 = h358 (zero weight)
  int ki = (k < 143) ? k : k - 2;
  float w = W[o*296 + ki];
  if (M) w *= (float)M[o*296 + ki];
  return w;
}

__global__ void prep_kernel(
    const float* __restrict__ wi, const float* __restrict__ wr,
    const float* __restrict__ w10,const float* __restrict__ w20,const float* __restrict__ wa0,const float* __restrict__ wb0,const int* __restrict__ m0,
    const float* __restrict__ w11,const float* __restrict__ w21,const float* __restrict__ wa1,const float* __restrict__ wb1,const int* __restrict__ m1,
    const float* __restrict__ w12,const float* __restrict__ w22,const float* __restrict__ wa2,const float* __restrict__ wb2,const int* __restrict__ m2,
    u32* __restrict__ ws)
{
  for (int i = blockIdx.x*blockDim.x + threadIdx.x; i < WS_WORDS; i += gridDim.x*blockDim.x){
    float lo = 0.f, hi = 0.f;
    if (i < OFF1){
      int k2 = i >> 11, r = i & 2047;
      lo = lstmval(wi, wr, r, 2*k2);
      hi = lstmval(wi, wr, r, 2*k2+1);
    } else if (i < OFF2){
      int loc = i - OFF1;
      int k2 = loc / NT0P, rem = loc - k2*NT0P;
      int o = rem >> 2, m = rem & 3;
      if (o < 216){
        const float* W = (m==0)?w10:(m==1)?w20:(m==2)?wa0:wb0;
        const int* M = (m < 2) ? m0 : nullptr;
        lo = l0val(W, M, o, 2*k2); hi = l0val(W, M, o, 2*k2+1);
      }
    } else if (i < OFF3){
      int loc = i - OFF2;
      int k2 = loc / NT1P, rem = loc - k2*NT1P;
      int o = rem >> 2, m = rem & 3;
      if (o < 143){
        const float* W = (m==0)?w11:(m==1)?w21:(m==2)?wa1:wb1;
        const int* M = (m < 2) ? m1 : nullptr;
        lo = l1val(W, M, o, 2*k2); hi = l1val(W, M, o, 2*k2+1);
      }
    } else {
      int loc = i - OFF3;
      int k2 = loc / NT2P, rem = loc - k2*NT2P;
      int o = rem >> 2, m = rem & 3;
      if (o < 153){
        const float* W = (m==0)?w12:(m==1)?w22:(m==2)?wa2:wb2;
        const int* M = (m < 2) ? m2 : nullptr;
        lo = l2val(W, M, o, 2*k2); hi = l2val(W, M, o, 2*k2+1);
      }
    }
    ws[i] = packbf(lo, hi);
  }
}

// ---------------- persistent recurrent kernel ----------------
// grid 64, block 1024. thread: b = tid&1, v = tid>>1. Wave-private LDS rings
// fed by global_load_lds with counted vmcnt waits; raw barriers (no vm drain)
// so each phase's ring prologue is issued during the previous phase's tail.
__global__ __launch_bounds__(1024) void liquid_rnn(
    const float* __restrict__ x, const float* __restrict__ dtp,
    const float* __restrict__ lstm_bi,
    const float* __restrict__ b10, const float* __restrict__ b20,
    const float* __restrict__ ba0, const float* __restrict__ bb0,
    const float* __restrict__ b11, const float* __restrict__ b21,
    const float* __restrict__ ba1, const float* __restrict__ bb1,
    const float* __restrict__ b12, const float* __restrict__ b22,
    const float* __restrict__ ba2, const float* __restrict__ bb2,
    const u32* __restrict__ ws, float* __restrict__ out)
{
  __shared__ __align__(16) u32 ring[16][1536];   // 6 slots x 1KB per wave (96 KiB)
  __shared__ __align__(16) u32 hz[2][264];       // [xt pairs(5) | h_rec pairs(257) | pad]
  __shared__ __align__(16) u32 hlp[2][264];      // packed LSTM h (+ zero pad)
  __shared__ __align__(16) float zf[2][2048];    // LSTM gate pre-acts; reused for h out

  const int tid = threadIdx.x;
  const int b   = tid & 1;
  const int v   = tid >> 1;
  const int bg  = blockIdx.x*2 + b;
  const int w   = tid >> 6;        // wave id 0..15
  const int l   = tid & 63;        // lane
  const int vv  = v & 31;          // v within wave

  // hoisted biases
  const float lb0 = lstm_bi[4*v+0], lb1 = lstm_bi[4*v+1];
  const float lb2 = lstm_bi[4*v+2], lb3 = lstm_bi[4*v+3];
  float cb10=0,cb20=0,cba0=0,cbb0=0, cb11=0,cb21=0,cba1=0,cbb1=0, cb12=0,cb22=0,cba2=0,cbb2=0;
  if (v < 216){ cb10=b10[v]; cb20=b20[v]; cba0=ba0[v]; cbb0=bb0[v]; }
  if (v < 143){ cb11=b11[v]; cb21=b21[v]; cba1=ba1[v]; cbb1=bb1[v]; }
  if (v < 153){ cb12=b12[v]; cb22=b22[v]; cba2=ba2[v]; cbb2=bb2[v]; }

  // per-lane glds source byte offsets
  const u32 lo1  = (u32)((((l>>5)*2048) + (w<<7) + ((l&31)<<2)) << 2);
  const u32 lo3  = (u32)((((l>>5)*896 ) + (w<<7) + ((l&31)<<2)) << 2);
  const u32 lo57 = (u32)((((l>>5)*640 ) + (w<<7) + ((l&31)<<2)) << 2);
  const char* wzB  = (const char*)ws;
  const char* wl0B = (const char*)(ws + OFF1);
  const char* wl1B = (const char*)(ws + OFF2);
  const char* wl2B = (const char*)(ws + OFF3);

  // init LDS: zeros (h0 = 0), then xt(0)
  if (v < 264){ hz[b][v] = 0u; hlp[b][v] = 0u; }
  if (v < 5){
    int k0 = 2*v, k1 = k0+1;
    float e0 = (k0 < 8) ? x[(size_t)bg*TT*8 + k0] : dtp[(size_t)bg*TT];
    float e1 = (k1 < 8) ? x[(size_t)bg*TT*8 + k1] : 0.f;
    hz[b][v] = packbf(e0, e1);
  }
  float creg = 0.f;
  block_sync();

  // t=0 phase-1 prologue
  for (int j = 0; j < 6; ++j) gl16(wzB + (size_t)j*16384 + lo1, &ring[w][j<<8]);

  for (int t = 0; t < TT; ++t){
    // ---- phase 1: LSTM gate dots (rows 4v..4v+3) ----
    {
      float a0=lb0, a1=lb1, a2=lb2, a3=lb3;
      int slot = 0;
      #pragma unroll 1
      for (int c = 0; c < 132; ++c){
        waitvm<5>();
        uint2 av = *(const uint2*)&hz[b][2*c];
        const u32* sp = &ring[w][slot<<8];
        uint4 W0 = *(const uint4*)(sp + (vv<<2));
        uint4 W1 = *(const uint4*)(sp + 128 + (vv<<2));
        a0=bdot(W0.x,av.x,a0); a1=bdot(W0.y,av.x,a1); a2=bdot(W0.z,av.x,a2); a3=bdot(W0.w,av.x,a3);
        a0=bdot(W1.x,av.y,a0); a1=bdot(W1.y,av.y,a1); a2=bdot(W1.z,av.y,a2); a3=bdot(W1.w,av.y,a3);
        if (c < 126){
          gl16(wzB + (size_t)(c+6)*16384 + lo1, &ring[w][slot<<8]);
        } else {
          int j = c - 126;
          if (w < 7) gl16(wl0B + (size_t)j*7168 + lo3, &ring[w][j<<8]);     // ph3 prologue
          else       gl16(wzB  + (size_t)j*16384 + lo1, &ring[w][j<<8]);    // next-step ph1
        }
        slot = (slot == 5) ? 0 : slot + 1;
      }
      *(float4*)&zf[b][v<<2] = make_float4(a0,a1,a2,a3);
    }
    block_sync();
    // ---- phase 2: LSTM pointwise, pack h_lstm ----
    {
      float zi  = zf[b][v],       zig = zf[b][v+512];
      float zfg = zf[b][v+1024],  zog = zf[b][v+1536];
      creg = creg * sigm(zfg + 1.0f) + tanh_(zi) * sigm(zig);
      float hl = tanh_(creg) * sigm(zog);
      float part = __shfl_down(hl, 2);
      if (!(v & 1)) hlp[b][v>>1] = packbf(hl, part);
    }
    block_sync();
    // ---- phase 3: CfC L0 dots + fused combine -> i0 (waves 0..6) ----
    if (w < 7){
      float A0=cb10, A1=cb20, A2=cba0, A3=cbb0;
      int slot = 0;
      #pragma unroll 1
      for (int c = 0; c < 60; ++c){
        waitvm<5>();
        int ka = 2*c, kb = 2*c+1;
        u32 axl = (ka < 5) ? hz[b][ka] : hlp[b][ka-5];
        u32 axh = (kb < 5) ? hz[b][kb] : hlp[b][kb-5];
        const u32* sp = &ring[w][slot<<8];
        uint4 q0 = *(const uint4*)(sp + (vv<<2));
        uint4 q1 = *(const uint4*)(sp + 128 + (vv<<2));
        A0=bdot(q0.x,axl,A0); A1=bdot(q0.y,axl,A1); A2=bdot(q0.z,axl,A2); A3=bdot(q0.w,axl,A3);
        A0=bdot(q1.x,axh,A0); A1=bdot(q1.y,axh,A1); A2=bdot(q1.z,axh,A2); A3=bdot(q1.w,axh,A3);
        if (c < 54){
          gl16(wl0B + (size_t)(c+6)*7168 + lo3, &ring[w][slot<<8]);
        } else {
          int j = c - 54;
          if (w < 5) gl16(wl1B + (size_t)j*5120 + lo57, &ring[w][j<<8]);    // ph5 prologue
          else       gl16(wzB  + (size_t)j*16384 + lo1, &ring[w][j<<8]);    // next-step ph1
        }
        slot = (slot == 5) ? 0 : slot + 1;
      }
      float ti = sigm(A3 - A2);
      float o  = tanh_(A0)*(1.f - ti) + ti*tanh_(A1);
      float oh = __shfl_down(o, 2);
      if (v < 216){
        if (!(v & 1)) hz[b][5 + (v>>1)] = packbf(o, oh);
        if (t == TT-1) zf[b][v] = o;
      }
    }
    block_sync();
    // ---- phase 5: CfC L1 dots + fused combine -> i1 (waves 0..4); wave 8: xt prefetch ----
    if (w < 5){
      float A0=cb11, A1=cb21, A2=cba1, A3=cbb1;
      int slot = 0;
      #pragma unroll 1
      for (int c = 0; c < 96; ++c){
        waitvm<5>();
        int ka = 2*c, kb = 2*c+1;
        u32 axl = (ka < 108) ? hz[b][5+ka] : hlp[b][ka];
        u32 axh = (kb < 108) ? hz[b][5+kb] : hlp[b][kb];
        const u32* sp = &ring[w][slot<<8];
        uint4 q0 = *(const uint4*)(sp + (vv<<2));
        uint4 q1 = *(const uint4*)(sp + 128 + (vv<<2));
        A0=bdot(q0.x,axl,A0); A1=bdot(q0.y,axl,A1); A2=bdot(q0.z,axl,A2); A3=bdot(q0.w,axl,A3);
        A0=bdot(q1.x,axh,A0); A1=bdot(q1.y,axh,A1); A2=bdot(q1.z,axh,A2); A3=bdot(q1.w,axh,A3);
        if (c < 90) gl16(wl1B + (size_t)(c+6)*5120 + lo57, &ring[w][slot<<8]);
        else        gl16(wl2B + (size_t)(c-90)*5120 + lo57, &ring[w][(c-90)<<8]);  // ph7 prologue
        slot = (slot == 5) ? 0 : slot + 1;
      }
      float ti = sigm(A3 - A2);
      float o  = tanh_(A0)*(1.f - ti) + ti*tanh_(A1);
      float oh = __shfl_down(o, 2);
      if (v < 143){
        if (!(v & 1) && v < 142) hz[b][113 + (v>>1)] = packbf(o, oh);
        if (v == 142)            hz[b][184] = packbf(o, 0.f);
        if (t == TT-1) zf[b][216 + v] = o;
      }
    } else if (w == 8){
      if (t + 1 < TT && v < 261){
        int k0 = 2*(v-256), k1 = k0+1;
        float e0 = (k0 < 8) ? x[((size_t)bg*TT + t+1)*8 + k0] : dtp[(size_t)bg*TT + t+1];
        float e1 = (k1 < 8) ? x[((size_t)bg*TT + t+1)*8 + k1] : 0.f;
        hz[b][v-256] = packbf(e0, e1);
      }
    }
    block_sync();
    // ---- phase 7: CfC L2 dots + fused combine -> i2 (waves 0..4) ----
    if (w < 5){
      float A0=cb12, A1=cb22, A2=cba2, A3=cbb2;
      int slot = 0;
      #pragma unroll 1
      for (int c = 0; c < 78; ++c){
        waitvm<5>();
        int ka = 2*c, kb = 2*c+1;
        u32 axl = (ka < 72) ? hz[b][113+ka] : hlp[b][107+ka];
        u32 axh = (kb < 72) ? hz[b][113+kb] : hlp[b][107+kb];
        const u32* sp = &ring[w][slot<<8];
        uint4 q0 = *(const uint4*)(sp + (vv<<2));
        uint4 q1 = *(const uint4*)(sp + 128 + (vv<<2));
        A0=bdot(q0.x,axl,A0); A1=bdot(q0.y,axl,A1); A2=bdot(q0.z,axl,A2); A3=bdot(q0.w,axl,A3);
        A0=bdot(q1.x,axh,A0); A1=bdot(q1.y,axh,A1); A2=bdot(q1.z,axh,A2); A3=bdot(q1.w,axh,A3);
        if (c < 72) gl16(wl2B + (size_t)(c+6)*5120 + lo57, &ring[w][slot<<8]);
        else        gl16(wzB + (size_t)(c-72)*16384 + lo1, &ring[w][(c-72)<<8]);   // next-step ph1
        slot = (slot == 5) ? 0 : slot + 1;
      }
      float ti = sigm(A3 - A2);
      float o  = tanh_(A0)*(1.f - ti) + ti*tanh_(A1);
      float oh = __shfl_down(o, 2);
      if (v < 153){
        if (!(v & 1)){ float hi = (v == 152) ? 0.f : oh; hz[b][185 + (v>>1)] = packbf(o, hi); }
        if (t == TT-1) zf[b][359 + v] = o;
      }
    }
    block_sync();
  }

  // epilogue: h from zf, c from creg (f32 outputs)
  waitvm<0>();
  out[(size_t)bg*LATENT + v] = zf[b][v];
  out[65536 + (size_t)bg*LATENT + v] = creg;
}

extern "C" void kernel_launch(void* const* d_in, const int* in_sizes, int n_in,
                              void* d_out, int out_size, void* d_ws, size_t ws_size,
                              hipStream_t stream)
{
  (void)in_sizes; (void)n_in; (void)out_size; (void)ws_size;
  const float* x   = (const float*)d_in[0];
  const float* dt  = (const float*)d_in[1];
  const float* wi  = (const float*)d_in[2];
  const float* wr  = (const float*)d_in[3];
  const float* bi  = (const float*)d_in[4];
  const float* w10 = (const float*)d_in[5];  const float* b10 = (const float*)d_in[6];
  const float* w20 = (const float*)d_in[7];  const float* b20 = (const float*)d_in[8];
  const float* wa0 = (const float*)d_in[9];  const float* ba0 = (const float*)d_in[10];
  const float* wb0 = (const float*)d_in[11]; const float* bb0 = (const float*)d_in[12];
  const float* w11 = (const float*)d_in[13]; const float* b11 = (const float*)d_in[14];
  const float* w21 = (const float*)d_in[15]; const float* b21 = (const float*)d_in[16];
  const float* wa1 = (const float*)d_in[17]; const float* ba1 = (const float*)d_in[18];
  const float* wb1 = (const float*)d_in[19]; const float* bb1 = (const float*)d_in[20];
  const float* w12 = (const float*)d_in[21]; const float* b12 = (const float*)d_in[22];
  const float* w22 = (const float*)d_in[23]; const float* b22 = (const float*)d_in[24];
  const float* wa2 = (const float*)d_in[25]; const float* ba2 = (const float*)d_in[26];
  const float* wb2 = (const float*)d_in[27]; const float* bb2 = (const float*)d_in[28];
  const int* m0 = (const int*)d_in[29];
  const int* m1 = (const int*)d_in[30];
  const int* m2 = (const int*)d_in[31];

  u32* ws    = (u32*)d_ws;         // needs WS_WORDS*4 ≈ 3.32 MiB
  float* out = (float*)d_out;      // f32: h[128*512] then c[128*512]

  prep_kernel<<<dim3(851), dim3(1024), 0, stream>>>(
      wi, wr,
      w10,w20,wa0,wb0,m0,
      w11,w21,wa1,wb1,m1,
      w12,w22,wa2,wb2,m2,
      ws);

  liquid_rnn<<<dim3(64), dim3(1024), 0, stream>>>(
      x, dt, bi,
      b10,b20,ba0,bb0,
      b11,b21,ba1,bb1,
      b12,b22,ba2,bb2,
      ws, out);
}

// Round 5
// 16910.454 us; speedup vs baseline: 1.0456x; 1.0254x over previous
//
#include <hip/hip_runtime.h>
#include <stdint.h>

typedef unsigned int u32;
typedef unsigned short u16;

// ---- problem dims ----
#define TT     256
#define LATENT 512
// padded k2 (bf16-pair word) counts per layer, all multiples of 4 (uint4 groups)
#define KZ2P 272    // LSTM xc: slots [xt(9),pad, h0..h358, pad, h359..h511, pad...] = 544 slots
#define K0R  128    // L0 xc: 113 real words
#define K1R  192    // L1 xc: 180 real words
#define K2R  160    // L2 xc: 149 real words
// ws layout (u32 words). LSTM region is [k2][2048] with GATE-INTERLEAVED rows:
// ws row r = 4v+g  <->  original z row v + 512*g. CfC regions are row-major
// [tau][K] with tau = 4*o + m, m in {w1,w2,wa,wb}.
#define OFF_A (KZ2P*2048)           // 557056  (end LSTM)
#define OFF_B (OFF_A + 864*K0R)     // 667648  (end L0)
#define OFF_C (OFF_B + 572*K1R)     // 777472  (end L1)
#define WS_WORDS (OFF_C + 612*K2R)  // 875392  (~3.34 MiB)

__device__ __forceinline__ u16 f2bf(float f){
  u32 u = __builtin_bit_cast(u32, f);
  u += 0x7FFFu + ((u >> 16) & 1u);     // RNE
  return (u16)(u >> 16);
}
__device__ __forceinline__ u32 packbf(float lo, float hi){
  return (u32)f2bf(lo) | ((u32)f2bf(hi) << 16);
}
__device__ __forceinline__ float bdot(u32 a, u32 b, float c){
  float d;
  asm("v_dot2_f32_bf16 %0, %1, %2, %3" : "=v"(d) : "v"(a), "v"(b), "v"(c));
  return d;
}
__device__ __forceinline__ float sigm(float x){ return 1.0f/(1.0f + __expf(-x)); }
__device__ __forceinline__ float tanh_(float x){ return 1.0f - 2.0f/(1.0f + __expf(2.0f*x)); }

// ---------------- weight value mappings (proven in rounds 3/4) ----------------
__device__ __forceinline__ float lstmval(const float* wi, const float* wr, int r, int s){
  if (s < 9)  return wi[r*9 + s];
  if (s == 9 || s == 369 || s >= 523) return 0.f;
  if (s < 369) return wr[r*512 + s - 10];   // h0..h358
  return wr[r*512 + s - 11];                // h359..h511
}
__device__ __forceinline__ float l0val(const float* W, const int* M, int o, int k){
  if (k == 9 || k >= 226) return 0.f;
  int ki = (k < 9) ? k : k - 1;                 // D=225
  float w = W[o*225 + ki];
  if (M) w *= (float)M[o*225 + ki];
  return w;
}
__device__ __forceinline__ float l1val(const float* W, const int* M, int o, int k){
  if (k >= 359) return 0.f;                     // D=359
  float w = W[o*359 + k];
  if (M) w *= (float)M[o*359 + k];
  return w;
}
__device__ __forceinline__ float l2val(const float* W, const int* M, int o, int k){
  if (k == 143 || k == 144 || k >= 298) return 0.f;  // D=296; slot144 = h358 (zero weight)
  int ki = (k < 143) ? k : k - 2;
  float w = W[o*296 + ki];
  if (M) w *= (float)M[o*296 + ki];
  return w;
}

__global__ void prep_kernel(
    const float* __restrict__ wi, const float* __restrict__ wr,
    const float* __restrict__ w10,const float* __restrict__ w20,const float* __restrict__ wa0,const float* __restrict__ wb0,const int* __restrict__ m0,
    const float* __restrict__ w11,const float* __restrict__ w21,const float* __restrict__ wa1,const float* __restrict__ wb1,const int* __restrict__ m1,
    const float* __restrict__ w12,const float* __restrict__ w22,const float* __restrict__ wa2,const float* __restrict__ wb2,const int* __restrict__ m2,
    u32* __restrict__ ws)
{
  for (int i = blockIdx.x*blockDim.x + threadIdx.x; i < WS_WORDS; i += gridDim.x*blockDim.x){
    float lo = 0.f, hi = 0.f;
    if (i < OFF_A){
      int k2 = i >> 11, r = i & 2047;
      int orig = (r >> 2) + ((r & 3) << 9);     // gate-interleaved
      lo = lstmval(wi, wr, orig, 2*k2);
      hi = lstmval(wi, wr, orig, 2*k2+1);
    } else if (i < OFF_B){
      int loc = i - OFF_A;
      int r = loc >> 7, k2 = loc & 127;         // K0R=128
      int o = r >> 2, m = r & 3;
      const float* W = (m==0)?w10:(m==1)?w20:(m==2)?wa0:wb0;
      const int* M = (m < 2) ? m0 : nullptr;
      lo = l0val(W, M, o, 2*k2); hi = l0val(W, M, o, 2*k2+1);
    } else if (i < OFF_C){
      int loc = i - OFF_B;
      int r = loc / K1R, k2 = loc - r*K1R;
      int o = r >> 2, m = r & 3;
      const float* W = (m==0)?w11:(m==1)?w21:(m==2)?wa1:wb1;
      const int* M = (m < 2) ? m1 : nullptr;
      lo = l1val(W, M, o, 2*k2); hi = l1val(W, M, o, 2*k2+1);
    } else {
      int loc = i - OFF_C;
      int r = loc / K2R, k2 = loc - r*K2R;
      int o = r >> 2, m = r & 3;
      const float* W = (m==0)?w12:(m==1)?w22:(m==2)?wa2:wb2;
      const int* M = (m < 2) ? m2 : nullptr;
      lo = l2val(W, M, o, 2*k2); hi = l2val(W, M, o, 2*k2+1);
    }
    ws[i] = packbf(lo, hi);
  }
}

// ---------------- persistent recurrent kernel ----------------
// grid 64, block 1024. thread: b = tid&1, o/v = tid>>1. Adjacent lanes (b=0/1)
// read the SAME weight address -> coalescer dedup (512B unique per uint4 wave-load).
// Weights stream global->VGPR (no LDS round trip); activations are uint4 LDS
// broadcasts. 4 barriers/step. Dynamic-LDS pad forces 1 block/CU.
__global__ __launch_bounds__(1024) void liquid_rnn(
    const float* __restrict__ x, const float* __restrict__ dtp,
    const float* __restrict__ lstm_bi,
    const float* __restrict__ b10, const float* __restrict__ b20,
    const float* __restrict__ ba0, const float* __restrict__ bb0,
    const float* __restrict__ b11, const float* __restrict__ b21,
    const float* __restrict__ ba1, const float* __restrict__ bb1,
    const float* __restrict__ b12, const float* __restrict__ b22,
    const float* __restrict__ ba2, const float* __restrict__ bb2,
    const u32* __restrict__ ws, float* __restrict__ out)
{
  __shared__ u32 hz[2][KZ2P];     // LSTM xc words: [xt(5) | i0(108) | i1(72) | i2(77) | pad]
  __shared__ u32 xc0[2][K0R];     // L0 xc: [xt(5) | hl 0..215 (108) | pad]
  __shared__ u32 xc1[2][K1R];     // L1 xc: [i0 (108) | hl 216..359 (72) | pad]
  __shared__ u32 xc2[2][K2R];     // L2 xc: [i1 (72) | hl-tail (77) | pad]
  __shared__ float outh[2][512];  // final-step h staging

  const int tid = threadIdx.x;
  const int b   = tid & 1;
  const int v   = tid >> 1;
  const int bg  = blockIdx.x*2 + b;
  const int w   = tid >> 6;

  // hoisted biases (gate order i, ig, fg, og)
  const float lb0 = lstm_bi[v], lb1 = lstm_bi[v+512];
  const float lb2 = lstm_bi[v+1024], lb3 = lstm_bi[v+1536];
  float cb10=0,cb20=0,cba0=0,cbb0=0, cb11=0,cb21=0,cba1=0,cbb1=0, cb12=0,cb22=0,cba2=0,cbb2=0;
  if (v < 216){ cb10=b10[v]; cb20=b20[v]; cba0=ba0[v]; cbb0=bb0[v]; }
  if (v < 143){ cb11=b11[v]; cb21=b21[v]; cba1=ba1[v]; cbb1=bb1[v]; }
  if (v < 153){ cb12=b12[v]; cb22=b22[v]; cba2=ba2[v]; cbb2=bb2[v]; }

  const u32* wz  = ws;
  const u32* wl0 = ws + OFF_A;
  const u32* wl1 = ws + OFF_B;
  const u32* wl2 = ws + OFF_C;

  // init: zero LDS (pads + h0=0), then xt(0)
  if (v < KZ2P) hz[b][v] = 0u;
  if (v < K0R)  xc0[b][v] = 0u;
  if (v < K1R)  xc1[b][v] = 0u;
  if (v < K2R)  xc2[b][v] = 0u;
  if (v < 5){
    int k0 = 2*v, k1 = k0+1;
    float e0 = (k0 < 8) ? x[(size_t)bg*TT*8 + k0] : dtp[(size_t)bg*TT];
    float e1 = (k1 < 8) ? x[(size_t)bg*TT*8 + k1] : 0.f;
    hz[b][v] = packbf(e0, e1);
  }
  float creg = 0.f;
  __syncthreads();

  for (int t = 0; t < TT; ++t){
    // ---- P12: LSTM gates (thread v = neuron v, all 4 gates) + pointwise ----
    {
      float a0=lb0, a1=lb1, a2=lb2, a3=lb3;
      const u32* pw = wz + 4*v;
      #pragma unroll 2
      for (int g = 0; g < KZ2P/4; ++g){
        uint4 av = *(const uint4*)&hz[b][g<<2];
        const u32* q = pw + ((g<<2)*2048);
        uint4 w0 = *(const uint4*)q;
        uint4 w1 = *(const uint4*)(q + 2048);
        uint4 w2 = *(const uint4*)(q + 4096);
        uint4 w3 = *(const uint4*)(q + 6144);
        a0=bdot(w0.x,av.x,a0); a1=bdot(w0.y,av.x,a1); a2=bdot(w0.z,av.x,a2); a3=bdot(w0.w,av.x,a3);
        a0=bdot(w1.x,av.y,a0); a1=bdot(w1.y,av.y,a1); a2=bdot(w1.z,av.y,a2); a3=bdot(w1.w,av.y,a3);
        a0=bdot(w2.x,av.z,a0); a1=bdot(w2.y,av.z,a1); a2=bdot(w2.z,av.z,a2); a3=bdot(w2.w,av.z,a3);
        a0=bdot(w3.x,av.w,a0); a1=bdot(w3.y,av.w,a1); a2=bdot(w3.z,av.w,a2); a3=bdot(w3.w,av.w,a3);
      }
      creg = creg * sigm(a2 + 1.0f) + tanh_(a0) * sigm(a1);
      float hl = tanh_(creg) * sigm(a3);
      float part = __shfl_down(hl, 2);
      if (!(v & 1)){
        int j = v >> 1;  u32 pk = packbf(hl, part);
        if (j < 108) xc0[b][5+j] = pk;
        else if (j < 180){ xc1[b][j] = pk; if (j == 179) xc2[b][72] = pk; }
        else xc2[b][j-107] = pk;
      }
      if (tid < 10) xc0[b][v] = hz[b][v];    // xt prefix for L0
    }
    __syncthreads();
    // ---- P3: CfC L0 (thread o = output o; 4 fused dots + combine) ----
    if (tid < 432){
      float A0=cb10, A1=cb20, A2=cba0, A3=cbb0;
      const u32* p = wl0 + v*(4*K0R);
      #pragma unroll 2
      for (int g = 0; g < K0R/4; ++g){
        uint4 av = *(const uint4*)&xc0[b][g<<2];
        const u32* q = p + (g<<2);
        uint4 w0 = *(const uint4*)q;
        uint4 w1 = *(const uint4*)(q + K0R);
        uint4 w2 = *(const uint4*)(q + 2*K0R);
        uint4 w3 = *(const uint4*)(q + 3*K0R);
        A0=bdot(w0.x,av.x,A0); A0=bdot(w0.y,av.y,A0); A0=bdot(w0.z,av.z,A0); A0=bdot(w0.w,av.w,A0);
        A1=bdot(w1.x,av.x,A1); A1=bdot(w1.y,av.y,A1); A1=bdot(w1.z,av.z,A1); A1=bdot(w1.w,av.w,A1);
        A2=bdot(w2.x,av.x,A2); A2=bdot(w2.y,av.y,A2); A2=bdot(w2.z,av.z,A2); A2=bdot(w2.w,av.w,A2);
        A3=bdot(w3.x,av.x,A3); A3=bdot(w3.y,av.y,A3); A3=bdot(w3.z,av.z,A3); A3=bdot(w3.w,av.w,A3);
      }
      float ti = sigm(A3 - A2);
      float o0 = tanh_(A0)*(1.f - ti) + ti*tanh_(A1);
      float oh = __shfl_down(o0, 2);
      if (!(v & 1)){ u32 pk = packbf(o0, oh); hz[b][5+(v>>1)] = pk; xc1[b][v>>1] = pk; }
      if (t == TT-1) outh[b][v] = o0;
    }
    __syncthreads();
    // ---- P5: CfC L1 -> i1; wave 8 prefetches xt(t+1) ----
    if (tid < 286){
      float A0=cb11, A1=cb21, A2=cba1, A3=cbb1;
      const u32* p = wl1 + v*(4*K1R);
      #pragma unroll 2
      for (int g = 0; g < K1R/4; ++g){
        uint4 av = *(const uint4*)&xc1[b][g<<2];
        const u32* q = p + (g<<2);
        uint4 w0 = *(const uint4*)q;
        uint4 w1 = *(const uint4*)(q + K1R);
        uint4 w2 = *(const uint4*)(q + 2*K1R);
        uint4 w3 = *(const uint4*)(q + 3*K1R);
        A0=bdot(w0.x,av.x,A0); A0=bdot(w0.y,av.y,A0); A0=bdot(w0.z,av.z,A0); A0=bdot(w0.w,av.w,A0);
        A1=bdot(w1.x,av.x,A1); A1=bdot(w1.y,av.y,A1); A1=bdot(w1.z,av.z,A1); A1=bdot(w1.w,av.w,A1);
        A2=bdot(w2.x,av.x,A2); A2=bdot(w2.y,av.y,A2); A2=bdot(w2.z,av.z,A2); A2=bdot(w2.w,av.w,A2);
        A3=bdot(w3.x,av.x,A3); A3=bdot(w3.y,av.y,A3); A3=bdot(w3.z,av.z,A3); A3=bdot(w3.w,av.w,A3);
      }
      float ti = sigm(A3 - A2);
      float o0 = tanh_(A0)*(1.f - ti) + ti*tanh_(A1);
      float oh = __shfl_down(o0, 2);
      if (!(v & 1)){ u32 pk = packbf(o0, oh); hz[b][113+(v>>1)] = pk; xc2[b][v>>1] = pk; }
      if (t == TT-1) outh[b][216 + v] = o0;
    } else if (w == 8){
      if (t + 1 < TT && v < 261){
        int k0 = 2*(v-256), k1 = k0+1;
        float e0 = (k0 < 8) ? x[((size_t)bg*TT + t+1)*8 + k0] : dtp[(size_t)bg*TT + t+1];
        float e1 = (k1 < 8) ? x[((size_t)bg*TT + t+1)*8 + k1] : 0.f;
        hz[b][v-256] = packbf(e0, e1);
      }
    }
    __syncthreads();
    // ---- P7: CfC L2 -> i2 ----
    if (tid < 306){
      float A0=cb12, A1=cb22, A2=cba2, A3=cbb2;
      const u32* p = wl2 + v*(4*K2R);
      #pragma unroll 2
      for (int g = 0; g < K2R/4; ++g){
        uint4 av = *(const uint4*)&xc2[b][g<<2];
        const u32* q = p + (g<<2);
        uint4 w0 = *(const uint4*)q;
        uint4 w1 = *(const uint4*)(q + K2R);
        uint4 w2 = *(const uint4*)(q + 2*K2R);
        uint4 w3 = *(const uint4*)(q + 3*K2R);
        A0=bdot(w0.x,av.x,A0); A0=bdot(w0.y,av.y,A0); A0=bdot(w0.z,av.z,A0); A0=bdot(w0.w,av.w,A0);
        A1=bdot(w1.x,av.x,A1); A1=bdot(w1.y,av.y,A1); A1=bdot(w1.z,av.z,A1); A1=bdot(w1.w,av.w,A1);
        A2=bdot(w2.x,av.x,A2); A2=bdot(w2.y,av.y,A2); A2=bdot(w2.z,av.z,A2); A2=bdot(w2.w,av.w,A2);
        A3=bdot(w3.x,av.x,A3); A3=bdot(w3.y,av.y,A3); A3=bdot(w3.z,av.z,A3); A3=bdot(w3.w,av.w,A3);
      }
      float ti = sigm(A3 - A2);
      float o0 = tanh_(A0)*(1.f - ti) + ti*tanh_(A1);
      float oh = __shfl_down(o0, 2);
      if (!(v & 1)) hz[b][185+(v>>1)] = packbf(o0, oh);
      if (t == TT-1) outh[b][359 + v] = o0;
    }
    __syncthreads();
  }

  out[(size_t)bg*LATENT + v] = outh[b][v];
  out[65536 + (size_t)bg*LATENT + v] = creg;
}

extern "C" void kernel_launch(void* const* d_in, const int* in_sizes, int n_in,
                              void* d_out, int out_size, void* d_ws, size_t ws_size,
                              hipStream_t stream)
{
  (void)in_sizes; (void)n_in; (void)out_size; (void)ws_size;
  const float* x   = (const float*)d_in[0];
  const float* dt  = (const float*)d_in[1];
  const float* wi  = (const float*)d_in[2];
  const float* wr  = (const float*)d_in[3];
  const float* bi  = (const float*)d_in[4];
  const float* w10 = (const float*)d_in[5];  const float* b10 = (const float*)d_in[6];
  const float* w20 = (const float*)d_in[7];  const float* b20 = (const float*)d_in[8];
  const float* wa0 = (const float*)d_in[9];  const float* ba0 = (const float*)d_in[10];
  const float* wb0 = (const float*)d_in[11]; const float* bb0 = (const float*)d_in[12];
  const float* w11 = (const float*)d_in[13]; const float* b11 = (const float*)d_in[14];
  const float* w21 = (const float*)d_in[15]; const float* b21 = (const float*)d_in[16];
  const float* wa1 = (const float*)d_in[17]; const float* ba1 = (const float*)d_in[18];
  const float* wb1 = (const float*)d_in[19]; const float* bb1 = (const float*)d_in[20];
  const float* w12 = (const float*)d_in[21]; const float* b12 = (const float*)d_in[22];
  const float* w22 = (const float*)d_in[23]; const float* b22 = (const float*)d_in[24];
  const float* wa2 = (const float*)d_in[25]; const float* ba2 = (const float*)d_in[26];
  const float* wb2 = (const float*)d_in[27]; const float* bb2 = (const float*)d_in[28];
  const int* m0 = (const int*)d_in[29];
  const int* m1 = (const int*)d_in[30];
  const int* m2 = (const int*)d_in[31];

  u32* ws    = (u32*)d_ws;         // needs WS_WORDS*4 ≈ 3.34 MiB
  float* out = (float*)d_out;      // f32: h[128*512] then c[128*512]

  prep_kernel<<<dim3(856), dim3(1024), 0, stream>>>(
      wi, wr,
      w10,w20,wa0,wb0,m0,
      w11,w21,wa1,wb1,m1,
      w12,w22,wa2,wb2,m2,
      ws);

  // 72 KiB dynamic LDS (unused) + ~11 KiB static forces 1 block/CU.
  liquid_rnn<<<dim3(64), dim3(1024), 73728, stream>>>(
      x, dt, bi,
      b10,b20,ba0,bb0,
      b11,b21,ba1,bb1,
      b12,b22,ba2,bb2,
      ws, out);
}